// Round 8
// baseline (410.280 us; speedup 1.0000x reference)
//
#include <hip/hip_runtime.h>
#include <hip/hip_bf16.h>

#define B_ 16
#define C_ 256
#define L_ 2048
#define KVB 32              // m-tile per iteration
#define NT (L_ / KVB)       // 64 tiles

typedef __attribute__((ext_vector_type(8))) short bf16x8;
typedef __attribute__((ext_vector_type(4))) unsigned u32x4;
typedef __attribute__((ext_vector_type(16))) float f32x16;

#define CEXP 0.09016844005556021f   // (1/16) * log2(e), folded into Q conversion

// round-to-nearest-even float -> bf16
__device__ __forceinline__ short f2bf_rne(float f) {
    union { float f; unsigned u; } x; x.f = f;
    unsigned r = x.u + 0x7fffu + ((x.u >> 16) & 1u);
    return (short)(r >> 16);
}

__device__ __forceinline__ unsigned pack2(float lo, float hi) {
    return (unsigned)(unsigned short)f2bf_rne(lo)
         | ((unsigned)(unsigned short)f2bf_rne(hi) << 16);
}

// direct global->LDS DMA, 16 bytes per lane; LDS dest = wave-uniform base + lane*16
__device__ __forceinline__ void gld_lds16(const void* g, void* l) {
    __builtin_amdgcn_global_load_lds(
        (const __attribute__((address_space(1))) void*)g,
        (__attribute__((address_space(3))) void*)l, 16, 0, 0);
}

// ---------------- prepass: K transpose+cvt (blocks 0..511), V*mask cvt (512..4607) ----------
__global__ __launch_bounds__(256) void prepass_kernel(
        const float* __restrict__ Kin, const float* __restrict__ Vin,
        const float* __restrict__ mask,
        short* __restrict__ Kt, short* __restrict__ Vb) {
    const int bid = blockIdx.x;
    const int t = threadIdx.x;
    if (bid < 512) {
        __shared__ unsigned short tile[64 * 256];   // 32 KB; phys 16B-chunk = ck ^ (l&31)
        const int b  = bid >> 5;
        const int l0 = (bid & 31) * 64;
        #pragma unroll
        for (int iter = 0; iter < 8; ++iter) {
            int l  = t & 63;                       // 0..63
            int ck = (t >> 6) + 4 * iter;          // 0..31 (8-c chunk)
            const float* src = Kin + ((size_t)(b * C_ + 8 * ck)) * L_ + l0 + l;
            unsigned pk[4];
            #pragma unroll
            for (int jj = 0; jj < 4; ++jj) {
                float f0 = src[(size_t)(2 * jj) * L_];
                float f1 = src[(size_t)(2 * jj + 1) * L_];
                pk[jj] = pack2(f0, f1);
            }
            uint4 o = {pk[0], pk[1], pk[2], pk[3]};
            *(uint4*)(tile + l * 256 + ((ck ^ (l & 31)) << 3)) = o;
        }
        __syncthreads();
        #pragma unroll
        for (int iter = 0; iter < 8; ++iter) {
            int li = iter * 8 + (t >> 5);          // 0..63
            int ck = t & 31;                       // logical 16-B chunk
            uint4 val = *(const uint4*)(tile + li * 256 + ((ck ^ (li & 31)) << 3));
            *(uint4*)(Kt + ((size_t)(b * L_ + l0 + li)) * C_ + ck * 8) = val;
        }
    } else {
        // 4096 blocks x 256 threads x 8 elems = B_*C_*L_
        size_t e = ((size_t)(bid - 512) * 256 + t) * 8;
        int b = (int)(e >> 19);
        int m = (int)(e & (L_ - 1));
        const float4 v0 = *(const float4*)(Vin + e);
        const float4 v1 = *(const float4*)(Vin + e + 4);
        const float* mp = mask + ((size_t)b << 11) + m;
        const float4 m0 = *(const float4*)mp;
        const float4 m1 = *(const float4*)(mp + 4);
        uint4 o;
        o.x = pack2(v0.x * m0.x, v0.y * m0.y);
        o.y = pack2(v0.z * m0.z, v0.w * m0.w);
        o.z = pack2(v1.x * m1.x, v1.y * m1.y);
        o.w = pack2(v1.z * m1.z, v1.w * m1.w);
        *(uint4*)(Vb + e) = o;
    }
}

// ---- stage one 32-row K tile via DMA; XOR swizzle on the GLOBAL side ----
// K LDS: [m 0..31][slot p 0..31 of 16B]; phys slot p holds global chunk p ^ m.
__device__ __forceinline__ void stage_K(const short* __restrict__ Ksrc,
                                        short* Ks, int m0, int t) {
    #pragma unroll
    for (int rr = 0; rr < 4; ++rr) {
        int G = rr * 256 + t;                  // 0..1023
        int m = G >> 5, p = G & 31;
        gld_lds16(Ksrc + ((size_t)(m0 + m) << 8) + ((p ^ m) << 3), Ks + G * 8);
    }
}

// ---- stage one V tile (256 c x 32 m bf16 = 16 KB) via DMA ----
// V LDS: [c 0..255][slot p 0..3 of 16B]; phys slot p holds global chunk p ^ ((c>>1)&3).
// Read quad(lane) = 4*(ln&1) + (h ^ ((ln>>1)&3)) -> bijection per 8 lanes (round-5 fix).
__device__ __forceinline__ void stage_V(const short* __restrict__ Vsrc,
                                        short* Vs, int m0, int t) {
    #pragma unroll
    for (int rr = 0; rr < 4; ++rr) {
        int G = rr * 256 + t;                  // 0..1023
        int c = G >> 2, p = G & 3;
        gld_lds16(Vsrc + (size_t)c * L_ + m0 + ((p ^ ((c >> 1) & 3)) << 3), Vs + G * 8);
    }
}

// ---- per-tile body ----
// S' = mfma(A=K, B=Q): lane (ln,h) holds S'[m0 + mr(r,h)][l = lw+ln], mr(r,h)=(r&3)+8(r>>2)+4h.
// softmax lane-local; P redistributed across h-halves via 4 shfl_xor into B-frags b1,b2;
// O = mfma(A=V from LDS, B=P): D[row=c][col=l], 1 contiguous 16-B V chunk per lane per MFMA.
#define TILE_BODY(KS, VS, M0)                                                               \
  {                                                                                         \
    const short* Krow = (KS) + ln * 256;                                                    \
    bf16x8 kf[16];                                                                          \
    _Pragma("unroll")                                                                       \
    for (int ki = 0; ki < 16; ++ki)                                                         \
      kf[ki] = *(const bf16x8*)(Krow + (((2 * ki + h) ^ ln) << 3));                         \
    float4 mk[4];                                                                           \
    _Pragma("unroll")                                                                       \
    for (int s = 0; s < 4; ++s) mk[s] = *(const float4*)(mrow + (M0) + 8 * s + 4 * h);      \
    f32x16 s0 = z16, s1 = z16;                                                              \
    _Pragma("unroll")                                                                       \
    for (int ki = 0; ki < 8; ++ki)                                                          \
      s0 = __builtin_amdgcn_mfma_f32_32x32x16_bf16(kf[ki], qf[ki], s0, 0, 0, 0);            \
    _Pragma("unroll")                                                                       \
    for (int ki = 8; ki < 16; ++ki)                                                         \
      s1 = __builtin_amdgcn_mfma_f32_32x32x16_bf16(kf[ki], qf[ki], s1, 0, 0, 0);            \
    unsigned wds[8];                                                                        \
    _Pragma("unroll")                                                                       \
    for (int u = 0; u < 8; ++u) {                                                           \
      const int ra = 2 * u, rb = 2 * u + 1;                                                 \
      float fa = (mk[ra >> 2][ra & 3] + 1e-9f) * exp2f(s0[ra] + s1[ra]);                    \
      float fb = (mk[rb >> 2][rb & 3] + 1e-9f) * exp2f(s0[rb] + s1[rb]);                    \
      dn += fa + fb;                                                                        \
      wds[u] = pack2(fa, fb);                                                               \
    }                                                                                       \
    unsigned e0 = __shfl_xor(h ? wds[0] : wds[2], 32, 64);                                  \
    unsigned e1 = __shfl_xor(h ? wds[1] : wds[3], 32, 64);                                  \
    unsigned e2 = __shfl_xor(h ? wds[4] : wds[6], 32, 64);                                  \
    unsigned e3 = __shfl_xor(h ? wds[5] : wds[7], 32, 64);                                  \
    u32x4 b1u = { h ? e0 : wds[0], h ? e1 : wds[1], h ? wds[2] : e0, h ? wds[3] : e1 };     \
    u32x4 b2u = { h ? e2 : wds[4], h ? e3 : wds[5], h ? wds[6] : e2, h ? wds[7] : e3 };     \
    bf16x8 b1 = __builtin_bit_cast(bf16x8, b1u);                                            \
    bf16x8 b2 = __builtin_bit_cast(bf16x8, b2u);                                            \
    const int vsw = (ln >> 1) & 3;                                                          \
    _Pragma("unroll")                                                                       \
    for (int ct = 0; ct < 8; ++ct) {                                                        \
      const short* Vrow = (VS) + (32 * ct + ln) * 32;                                       \
      bf16x8 av1 = *(const bf16x8*)(Vrow + ((h ^ vsw) << 3));                               \
      bf16x8 av2 = *(const bf16x8*)(Vrow + (((2 + h) ^ vsw) << 3));                         \
      Oacc[ct] = __builtin_amdgcn_mfma_f32_32x32x16_bf16(av1, b1, Oacc[ct], 0, 0, 0);       \
      Oacc[ct] = __builtin_amdgcn_mfma_f32_32x32x16_bf16(av2, b2, Oacc[ct], 0, 0, 0);       \
    }                                                                                       \
  }

// ---------------- main fused attention ----------------------------------------------------
// split=0: 256 blocks, full KV range, direct scaled store (round-7 path).
// split=1: 512 blocks, half = bid>>8 processes m in [1024*half, +1024); unscaled fp32
//          O-partials + partial denom -> workspace; combine kernel finishes.
//          2 blocks/CU (LDS 2x64KB=128<=160, VGPR 208<=256 @ 2 waves/SIMD) -> 2 waves/SIMD.
__global__ __launch_bounds__(256, 2) void attn_main(
        const float* __restrict__ Qin,  // [B][C][L] fp32
        const short* __restrict__ Kt,   // [B][L][C] bf16
        const short* __restrict__ Vb,   // [B][C][L] bf16, mask-scaled
        const float* __restrict__ mask, // [B][L]
        float* __restrict__ out,        // [B][C][L]
        float* __restrict__ Opart,      // [2][B][C][L] fp32 partials (split only)
        float* __restrict__ Dnpart,     // [2][B][L] fp32 partial denoms (split only)
        const int split) {
    __shared__ __align__(16) char smem[65536];
    short* KsB0 = (short*)smem;                 // 16 KB (even tiles)
    short* KsB1 = (short*)(smem + 16384);       // 16 KB (odd tiles)
    short* VsB0 = (short*)(smem + 32768);       // 16 KB (even tiles)
    short* VsB1 = (short*)(smem + 49152);       // 16 KB (odd tiles)

    const int t = threadIdx.x;
    const int w = t >> 6, lane = t & 63;
    const int ln = lane & 31, h = lane >> 5;

    int inner, half;
    if (split) { half = blockIdx.x >> 8; inner = blockIdx.x & 255; }
    else       { half = 0;               inner = blockIdx.x; }
    const int b  = inner & 15;                  // same-b blocks share an XCD (b&7)
    const int l0 = (inner >> 4) * 128;
    const int lw = l0 + 32 * w;                 // wave's l base

    const int m_base = half * (L_ / 2);
    const int n_it2  = split ? (NT / 4) : (NT / 2);
    const int m_end  = m_base + n_it2 * 2 * KVB;

    const short* Ksrc = Kt + (size_t)b * (L_ * C_);
    const short* Vsrc = Vb + (size_t)b * (C_ * L_);
    const float* mrow = mask + (size_t)b * L_;

    // deep prefetch: first tile (lands during Q gather)
    stage_K(Ksrc, KsB0, m_base, t);
    stage_V(Vsrc, VsB0, m_base, t);

    // Q B-frags: qf[ki] elem (h,j) = Q[c = 16ki+8h+j][l = lw+ln] * CEXP (one-time gather)
    bf16x8 qf[16];
    {
        const float* Qb = Qin + (size_t)b * (C_ * L_) + (lw + ln);
        #pragma unroll
        for (int ki = 0; ki < 16; ++ki) {
            bf16x8 v;
            #pragma unroll
            for (int j = 0; j < 8; ++j) {
                float f = Qb[(size_t)(16 * ki + 8 * h + j) * L_];
                v[j] = f2bf_rne(f * CEXP);
            }
            qf[ki] = v;
        }
    }

    const f32x16 z16 = {0.f,0.f,0.f,0.f,0.f,0.f,0.f,0.f,0.f,0.f,0.f,0.f,0.f,0.f,0.f,0.f};
    f32x16 Oacc[8];
    #pragma unroll
    for (int ct = 0; ct < 8; ++ct) Oacc[ct] = z16;
    float dn = 0.f;

    __syncthreads();   // first tile landed

    #pragma unroll 1
    for (int it2 = 0; it2 < n_it2; ++it2) {
        const int m0a = m_base + it2 * (2 * KVB);
        const int m0b = m0a + KVB;

        // even tile: compute from B0, prefetch m0b -> B1
        stage_K(Ksrc, KsB1, m0b, t);
        stage_V(Vsrc, VsB1, m0b, t);
        TILE_BODY(KsB0, VsB0, m0a)
        __syncthreads();

        // odd tile: compute from B1, prefetch m0b+KVB -> B0
        if (m0b + KVB < m_end) {
            stage_K(Ksrc, KsB0, m0b + KVB, t);
            stage_V(Vsrc, VsB0, m0b + KVB, t);
        }
        TILE_BODY(KsB1, VsB1, m0b)
        __syncthreads();
    }

    // ---- denominator: one cross-half exchange -> every lane holds this half's denom
    dn += __shfl_xor(dn, 32, 64);

    if (split) {
        if (h == 0) Dnpart[(size_t)half * (B_ * L_) + b * L_ + lw + ln] = dn;
        float* op = Opart + (size_t)half * ((size_t)B_ * C_ * L_)
                  + (size_t)b * (C_ * L_) + lw + ln;
        #pragma unroll
        for (int ct = 0; ct < 8; ++ct)
            #pragma unroll
            for (int r = 0; r < 16; ++r) {
                int c = 32 * ct + (r & 3) + 8 * (r >> 2) + 4 * h;
                op[(size_t)c * L_] = Oacc[ct][r];
            }
    } else {
        const float rden = 1.0f / dn;
        float* ob = out + (size_t)b * (C_ * L_) + lw + ln;
        #pragma unroll
        for (int ct = 0; ct < 8; ++ct)
            #pragma unroll
            for (int r = 0; r < 16; ++r) {
                int c = 32 * ct + (r & 3) + 8 * (r >> 2) + 4 * h;
                ob[(size_t)c * L_] = Oacc[ct][r] * rden;
            }
    }
}

// ---------------- combine: out = (O0 + O1) / (dn0 + dn1), vectorized float4 ---------------
__global__ __launch_bounds__(256) void combine_kernel(
        const float* __restrict__ Opart, const float* __restrict__ Dnpart,
        float* __restrict__ out) {
    size_t e = ((size_t)blockIdx.x * 256 + threadIdx.x) * 4;   // 8192 blocks cover B*C*L
    int b = (int)(e >> 19);                                    // C_*L_ = 2^19
    int l = (int)(e & (L_ - 1));
    float4 o0 = *(const float4*)(Opart + e);
    float4 o1 = *(const float4*)(Opart + (size_t)B_ * C_ * L_ + e);
    float4 d0 = *(const float4*)(Dnpart + b * L_ + l);
    float4 d1 = *(const float4*)(Dnpart + B_ * L_ + b * L_ + l);
    float4 r;
    r.x = (o0.x + o1.x) / (d0.x + d1.x);
    r.y = (o0.y + o1.y) / (d0.y + d1.y);
    r.z = (o0.z + o1.z) / (d0.z + d1.z);
    r.w = (o0.w + o1.w) / (d0.w + d1.w);
    *(float4*)(out + e) = r;
}

extern "C" void kernel_launch(void* const* d_in, const int* in_sizes, int n_in,
                              void* d_out, int out_size, void* d_ws, size_t ws_size,
                              hipStream_t stream) {
    const float* Q    = (const float*)d_in[0];
    const float* K    = (const float*)d_in[1];
    const float* V    = (const float*)d_in[2];
    const float* mask = (const float*)d_in[3];
    float* out = (float*)d_out;

    // workspace: Kt | Vb (bf16, 16 MiB each) | Opart (fp32, 64 MiB) | Dnpart (256 KiB)
    const size_t kv_bytes = (size_t)2 * B_ * L_ * C_ * sizeof(short);       // 33,554,432
    const size_t op_bytes = (size_t)2 * B_ * C_ * L_ * sizeof(float);       // 67,108,864
    const size_t dn_bytes = (size_t)2 * B_ * L_ * sizeof(float);            //    262,144
    short* Kt = (short*)d_ws;
    short* Vb = Kt + (size_t)B_ * L_ * C_;
    float* Op = (float*)((char*)d_ws + kv_bytes);
    float* Dn = (float*)((char*)d_ws + kv_bytes + op_bytes);
    const bool use_split = ws_size >= kv_bytes + op_bytes + dn_bytes;

    prepass_kernel<<<4608, 256, 0, stream>>>(K, V, mask, Kt, Vb);
    if (use_split) {
        attn_main<<<512, 256, 0, stream>>>(Q, Kt, Vb, mask, out, Op, Dn, 1);
        combine_kernel<<<8192, 256, 0, stream>>>(Op, Dn, out);
    } else {
        attn_main<<<256, 256, 0, stream>>>(Q, Kt, Vb, mask, out, nullptr, nullptr, 0);
    }
}